// Round 12
// baseline (576.002 us; speedup 1.0000x reference)
//
#include <hip/hip_runtime.h>
#include <hip/hip_bf16.h>
#include <cstddef>

// Problem constants (fixed by reference)
#define N_USERS   100000
#define N_ITEMS   100000
#define N_NODES   200000
#define D         64
#define BATCH     2048
#define HIST      50
#define N_ITEMS_PAD 100096   // padded to multiple of 128 (block item-chunk)

#define BUCKET_SHIFT 10                      // 1024 rows per bucket
#define BROWS (1 << BUCKET_SHIFT)
#define N_BUCKETS_RAW ((N_NODES + BROWS - 1) >> BUCKET_SHIFT)  // 196
#define CHUNK 8192                           // edges per binning block
#define EPT   (CHUNK / 256)                  // 32 edges per thread (8 x int4)
// Fixed bucket capacity: counts ~ Binomial(12.8M, 1024/200K): mean 65536, sigma 255.
// 73728 = mean + 32 sigma. Deterministic seed-0 dataset; guarded per-edge anyway.
#define BCAP 73728
// Half-bucket LDS output buffer: Binomial(12.8M, 512/200K) mean 32768 sigma 181;
// 36864 = +22 sigma. 144 KB of LDS.
#define HBUF 36864

// k_scores geometry: batch-stationary waves, item-streaming.
#define ISPLITS 92                           // 100096/32 = 3128 tiles = 92 * 34
#define TPS (N_ITEMS_PAD / 32 / ISPLITS)     // 34 item-tiles per x-block
#define LOG2E 1.44269504088896f

typedef __attribute__((ext_vector_type(8))) short short8;
typedef __attribute__((ext_vector_type(16))) float float16;
typedef __attribute__((ext_vector_type(2)))  float floatx2;

__device__ __forceinline__ float exp2fast(float x) {   // v_exp_f32 = 2^x
    return __builtin_amdgcn_exp2f(x);
}
__device__ __forceinline__ ushort f2bf(float x) {  // fp32 -> bf16 RNE
    unsigned u = __float_as_uint(x);
    return (ushort)((u + 0x7FFF + ((u >> 16) & 1)) >> 16);
}
__device__ __forceinline__ unsigned char f2fp8(float x) {  // fp32 -> fp8 e4m3 (OCP), RNE+sat
    int p = __builtin_amdgcn_cvt_pk_fp8_f32(x, x, 0, false);
    return (unsigned char)(p & 0xFF);
}
__device__ __forceinline__ float fp82f(unsigned char u) {  // fp8 e4m3 -> fp32
    return __builtin_amdgcn_cvt_f32_fp8((int)u, 0);
}

// ---------------- pass A: bin edges into fixed-capacity bucket arenas ----------------
// ONE return-LDS-atomic per edge: claim slot in LDS cursor, stash (slot<<18)|row in
// registers, reserve the block's bucket runs after a barrier, then place records
// (adj_col int4-reloaded, L2-warm). NO global atomics per edge (R2/R4 lesson).
__global__ __launch_bounds__(256) void k_binA(const int* __restrict__ adj_row,
                                              const int* __restrict__ adj_col,
                                              int* __restrict__ gcursor, int* __restrict__ staged,
                                              int nedges) {
    __shared__ int cur[N_BUCKETS_RAW];
    __shared__ int lbase[N_BUCKETS_RAW];
    int t = threadIdx.x;
    int base = blockIdx.x * CHUNK;
    for (int i = t; i < N_BUCKETS_RAW; i += 256) cur[i] = 0;
    __syncthreads();
    int stash[EPT];
#pragma unroll
    for (int k = 0; k < EPT / 4; ++k) {
        int e0 = base + (k * 256 + t) * 4;
        if (e0 + 3 < nedges) {
            int4 r4 = *(const int4*)(adj_row + e0);
            int p;
            p = atomicAdd(&cur[r4.x >> BUCKET_SHIFT], 1); stash[4 * k    ] = (p << 18) | r4.x;
            p = atomicAdd(&cur[r4.y >> BUCKET_SHIFT], 1); stash[4 * k + 1] = (p << 18) | r4.y;
            p = atomicAdd(&cur[r4.z >> BUCKET_SHIFT], 1); stash[4 * k + 2] = (p << 18) | r4.z;
            p = atomicAdd(&cur[r4.w >> BUCKET_SHIFT], 1); stash[4 * k + 3] = (p << 18) | r4.w;
        } else {
#pragma unroll
            for (int j = 0; j < 4; ++j) {
                int e = e0 + j;
                if (e < nedges) {
                    int r = adj_row[e];
                    int p = atomicAdd(&cur[r >> BUCKET_SHIFT], 1);
                    stash[4 * k + j] = (p << 18) | r;
                } else stash[4 * k + j] = -1;
            }
        }
    }
    __syncthreads();
    for (int b = t; b < N_BUCKETS_RAW; b += 256) {
        int c = cur[b];
        int s = (c > 0) ? atomicAdd(&gcursor[b], c) : 0;
        lbase[b] = b * BCAP + s;
    }
    __syncthreads();
#pragma unroll
    for (int k = 0; k < EPT / 4; ++k) {
        int e0 = base + (k * 256 + t) * 4;
        if (e0 + 3 < nedges) {
            int4 c4 = *(const int4*)(adj_col + e0);
#pragma unroll
            for (int j = 0; j < 4; ++j) {
                int v = stash[4 * k + j];
                int c = (j == 0) ? c4.x : (j == 1) ? c4.y : (j == 2) ? c4.z : c4.w;
                int r = v & 0x3FFFF;
                int b = r >> BUCKET_SHIFT;
                int pos = lbase[b] + (v >> 18);
                if (pos < (b + 1) * BCAP)             // overflow guard (never fires)
                    staged[pos] = ((r & (BROWS - 1)) << 18) | c;
            }
        } else {
#pragma unroll
            for (int j = 0; j < 4; ++j) {
                int v = stash[4 * k + j];
                if (v >= 0) {
                    int e = e0 + j;
                    int c = adj_col[e];
                    int r = v & 0x3FFFF;
                    int b = r >> BUCKET_SHIFT;
                    int pos = lbase[b] + (v >> 18);
                    if (pos < (b + 1) * BCAP)
                        staged[pos] = ((r & (BROWS - 1)) << 18) | c;
                }
            }
        }
    }
}

// ---------------- pass B v3: LDS-staged packed output (kills 3x write amp) ----------------
__global__ __launch_bounds__(1024) void k_binB(const int* __restrict__ gcursor, const int* __restrict__ staged,
                                               int* __restrict__ ecols, int* __restrict__ rowptr,
                                               int* __restrict__ deg,
                                               const float* __restrict__ user_emb,
                                               const float* __restrict__ item_emb,
                                               unsigned char* __restrict__ w0) {
    __shared__ int cnt[BROWS];        // 4 KB
    __shared__ int scn[BROWS];        // 4 KB
    __shared__ int cur[BROWS / 2];    // 2 KB
    __shared__ int lbuf[HBUF];        // 144 KB  (total 154 KB < 160 KB)
    int b = blockIdx.x, t = threadIdx.x;
    cnt[t] = 0;
    __syncthreads();
    int nb = gcursor[b]; if (nb > BCAP) nb = BCAP;
    size_t es = (size_t)b * BCAP;
    for (int e = t; e < nb; e += 1024) atomicAdd(&cnt[staged[es + e] >> 18], 1);
    __syncthreads();
    int myc = cnt[t];
    scn[t] = myc;
    __syncthreads();
    for (int off = 1; off < BROWS; off <<= 1) {
        int v = (t >= off) ? scn[t - off] : 0;
        __syncthreads();
        scn[t] += v;
        __syncthreads();
    }
    int r = (b << BUCKET_SHIFT) + t;
    if (r < N_NODES) { rowptr[r] = b * BCAP + scn[t] - myc; deg[r] = myc; }
    // two half-passes: place into LDS, then contiguous copy-out
    for (int h = 0; h < 2; ++h) {
        int hbase = h << 9;                            // 0 or 512
        int excl0 = (h == 0) ? 0 : scn[511];
        if (t < 512) cur[t] = scn[hbase + t] - cnt[hbase + t] - excl0;
        __syncthreads();
        for (int e = t; e < nb; e += 1024) {
            int v = staged[es + e];
            int rr = v >> 18;
            if ((rr >> 9) == h) {
                int lp = atomicAdd(&cur[rr & 511], 1);
                if (lp < HBUF)                          // overflow guard (never fires)
                    lbuf[lp] = (v & 0x3FFFF) << 6;      // byte offset into fp8 rows
            }
        }
        __syncthreads();
        int tot = ((h == 0) ? scn[511] : scn[BROWS - 1]) - excl0;
        if (tot > HBUF) tot = HBUF;
        int obase = b * BCAP + excl0;
        for (int i = t; i < tot; i += 1024) ecols[obase + i] = lbuf[i];
        __syncthreads();
    }
    // fused init for this bucket's rows (cnt[] is stable)
    int r0 = b << BUCKET_SHIFT;
    for (int f = t; f < BROWS * 16; f += 1024) {
        int lr = f >> 4;
        int row = r0 + lr;
        if (row >= N_NODES) continue;
        const float4* src = (row < N_USERS)
            ? ((const float4*)user_emb) + (size_t)row * 16 + (f & 15)
            : ((const float4*)item_emb) + (size_t)(row - (N_USERS - 1)) * 16 + (f & 15);
        float4 v = *src;
        int dg = cnt[lr]; if (dg < 1) dg = 1;
        float sc = 64.f * __frsqrt_rn((float)dg);
        uchar4 o;
        o.x = f2fp8(v.x * sc); o.y = f2fp8(v.y * sc);
        o.z = f2fp8(v.z * sc); o.w = f2fp8(v.w * sc);
        ((uchar4*)w0)[(size_t)row * 16 + (f & 15)] = o;
    }
}

// ---------------- propagate (fp8 z-space): w_out[r] = (1/deg_r) * sum w_in[c] ----------------
// v5: group-per-row (8 rows x 8 dim-lanes, no cross-lane reduce) + 16-deep gather
// pipeline. R11 PMC: 0.26 gathers/cyc/CU at depth-8, no pipe saturated -> in-flight
// (waves x depth) is binding; depth 8->16 doubles it. VGPR ~80 keeps 6 waves/SIMD.
#define ACC8(v)                                               \
    a01 += __builtin_amdgcn_cvt_pk_f32_fp8((int)(v).x, false); \
    a23 += __builtin_amdgcn_cvt_pk_f32_fp8((int)(v).x, true);  \
    a45 += __builtin_amdgcn_cvt_pk_f32_fp8((int)(v).y, false); \
    a67 += __builtin_amdgcn_cvt_pk_f32_fp8((int)(v).y, true);

__global__ __launch_bounds__(256) void k_prop(const int* __restrict__ rowptr, const int* __restrict__ deg,
                                              const int* __restrict__ ecols,
                                              const unsigned char* __restrict__ x_in,
                                              unsigned char* __restrict__ x_out) {
    int lane = threadIdx.x & 63;
    int row = blockIdx.x * 32 + (threadIdx.x >> 6) * 8 + (lane >> 3);
    int d8 = (lane & 7) * 8;       // 8 dims per lane
    int s = rowptr[row];
    int cnt = deg[row];
    const int* ec = ecols + s;
    const unsigned char* xb = x_in + d8;
    // wave-wide min/max of cnt across the 8 row-groups
    int cmin = cnt, cmax = cnt;
#pragma unroll
    for (int off = 8; off < 64; off <<= 1) {
        cmin = min(cmin, __shfl_xor(cmin, off));
        cmax = max(cmax, __shfl_xor(cmax, off));
    }
    floatx2 a01 = {0.f, 0.f}, a23 = {0.f, 0.f}, a45 = {0.f, 0.f}, a67 = {0.f, 0.f};
    int e = 0;
    for (; e + 16 <= cmin; e += 16) {  // unguarded bulk: 16 gathers in flight
        int c0 = ec[e];
        int c1 = ec[e + 1];
        int c2 = ec[e + 2];
        int c3 = ec[e + 3];
        int c4 = ec[e + 4];
        int c5 = ec[e + 5];
        int c6 = ec[e + 6];
        int c7 = ec[e + 7];
        int c8 = ec[e + 8];
        int c9 = ec[e + 9];
        int ca = ec[e + 10];
        int cb = ec[e + 11];
        int cc = ec[e + 12];
        int cd = ec[e + 13];
        int ce = ec[e + 14];
        int cf = ec[e + 15];
        uint2 v0 = *(const uint2*)(xb + c0);
        uint2 v1 = *(const uint2*)(xb + c1);
        uint2 v2 = *(const uint2*)(xb + c2);
        uint2 v3 = *(const uint2*)(xb + c3);
        uint2 v4 = *(const uint2*)(xb + c4);
        uint2 v5 = *(const uint2*)(xb + c5);
        uint2 v6 = *(const uint2*)(xb + c6);
        uint2 v7 = *(const uint2*)(xb + c7);
        uint2 v8 = *(const uint2*)(xb + c8);
        uint2 v9 = *(const uint2*)(xb + c9);
        uint2 va = *(const uint2*)(xb + ca);
        uint2 vb = *(const uint2*)(xb + cb);
        uint2 vc = *(const uint2*)(xb + cc);
        uint2 vd = *(const uint2*)(xb + cd);
        uint2 ve = *(const uint2*)(xb + ce);
        uint2 vf = *(const uint2*)(xb + cf);
        ACC8(v0) ACC8(v1) ACC8(v2) ACC8(v3)
        ACC8(v4) ACC8(v5) ACC8(v6) ACC8(v7)
        ACC8(v8) ACC8(v9) ACC8(va) ACC8(vb)
        ACC8(vc) ACC8(vd) ACC8(ve) ACC8(vf)
    }
    for (; e + 8 <= cmin; e += 8) {  // 8-deep remainder
        int c0 = ec[e];
        int c1 = ec[e + 1];
        int c2 = ec[e + 2];
        int c3 = ec[e + 3];
        int c4 = ec[e + 4];
        int c5 = ec[e + 5];
        int c6 = ec[e + 6];
        int c7 = ec[e + 7];
        uint2 v0 = *(const uint2*)(xb + c0);
        uint2 v1 = *(const uint2*)(xb + c1);
        uint2 v2 = *(const uint2*)(xb + c2);
        uint2 v3 = *(const uint2*)(xb + c3);
        uint2 v4 = *(const uint2*)(xb + c4);
        uint2 v5 = *(const uint2*)(xb + c5);
        uint2 v6 = *(const uint2*)(xb + c6);
        uint2 v7 = *(const uint2*)(xb + c7);
        ACC8(v0) ACC8(v1) ACC8(v2) ACC8(v3)
        ACC8(v4) ACC8(v5) ACC8(v6) ACC8(v7)
    }
    for (; e + 4 <= cmin; e += 4) {  // 4-deep remainder toward cmin
        int c0 = ec[e];
        int c1 = ec[e + 1];
        int c2 = ec[e + 2];
        int c3 = ec[e + 3];
        uint2 v0 = *(const uint2*)(xb + c0);
        uint2 v1 = *(const uint2*)(xb + c1);
        uint2 v2 = *(const uint2*)(xb + c2);
        uint2 v3 = *(const uint2*)(xb + c3);
        ACC8(v0) ACC8(v1) ACC8(v2) ACC8(v3)
    }
    for (; e < cmax; e += 2) {       // clamp+cndmask tail (group-uniform predicates)
        bool k0 = e < cnt, k1 = e + 1 < cnt;
        int c0 = ec[k0 ? e : 0];
        int c1 = ec[k1 ? e + 1 : 0];
        uint2 v0 = *(const uint2*)(xb + c0);
        uint2 v1 = *(const uint2*)(xb + c1);
        v0.x = k0 ? v0.x : 0u; v0.y = k0 ? v0.y : 0u;
        v1.x = k1 ? v1.x : 0u; v1.y = k1 ? v1.y : 0u;
        ACC8(v0) ACC8(v1)
    }
    float inv = (cnt > 0) ? 1.f / (float)cnt : 0.f;
    int w01 = __builtin_amdgcn_cvt_pk_fp8_f32(a01.x * inv, a01.y * inv, 0, false);
    w01     = __builtin_amdgcn_cvt_pk_fp8_f32(a23.x * inv, a23.y * inv, w01, true);
    int w23 = __builtin_amdgcn_cvt_pk_fp8_f32(a45.x * inv, a45.y * inv, 0, false);
    w23     = __builtin_amdgcn_cvt_pk_fp8_f32(a67.x * inv, a67.y * inv, w23, true);
    uint2 o; o.x = (unsigned)w01; o.y = (unsigned)w23;
    *(uint2*)(x_out + (size_t)row * D + d8) = o;   // 64B/row, contiguous per wave
}

// ---------------- item latents, fragment-tiled + log2e-scaled ----------------
__global__ void k_conv_items(const float* __restrict__ item_emb, const int* __restrict__ deg,
                             const unsigned char* __restrict__ w1, const unsigned char* __restrict__ w2,
                             const unsigned char* __restrict__ w3, ushort* __restrict__ item_bf) {
    int f = blockIdx.x * 256 + threadIdx.x;    // one 4-dim group
    if (f >= N_ITEMS_PAD * (D / 4)) return;
    int row = f >> 4, c4 = f & 15;
    ushort4 o;
    if (row < N_ITEMS) {
        int node = N_USERS + row;
        int dg = deg[node]; if (dg < 1) dg = 1;
        float s = sqrtf((float)dg) * (1.f / 256.f);    // sqrt(deg)/(64 scale * 4 avg)
        float4 e4 = ((const float4*)(item_emb + (size_t)(row + 1) * D))[c4];
        size_t n4 = (size_t)node * 16 + c4;
        uchar4 a = ((const uchar4*)w1)[n4];
        uchar4 b = ((const uchar4*)w2)[n4];
        uchar4 c = ((const uchar4*)w3)[n4];
        o.x = f2bf(LOG2E * (0.25f * e4.x + s * (fp82f(a.x) + fp82f(b.x) + fp82f(c.x))));
        o.y = f2bf(LOG2E * (0.25f * e4.y + s * (fp82f(a.y) + fp82f(b.y) + fp82f(c.y))));
        o.z = f2bf(LOG2E * (0.25f * e4.z + s * (fp82f(a.z) + fp82f(b.z) + fp82f(c.z))));
        o.w = f2bf(LOG2E * (0.25f * e4.w + s * (fp82f(a.w) + fp82f(b.w) + fp82f(c.w))));
    } else {
        o.x = o.y = o.z = o.w = 0;   // pad rows -> score 0 -> exp2 = 1 (subtract 96 in k_loss)
    }
    int tile = row >> 5, rr = row & 31;
    int q = c4 >> 2, half = (c4 >> 1) & 1, e0 = (c4 & 1) * 4;
    size_t idx = (size_t)tile * 2048 + q * 512 + (rr + 32 * half) * 8 + e0;
    *(ushort4*)(item_bf + idx) = o;
}

// ---------------- pred (bf16 copy) + label score ----------------
__global__ __launch_bounds__(256) void k_pred(const int* __restrict__ user_seqs, const int* __restrict__ his,
                                              const int* __restrict__ next_items,
                                              const float* __restrict__ user_emb, const float* __restrict__ item_emb,
                                              const int* __restrict__ deg,
                                              const unsigned char* __restrict__ w1, const unsigned char* __restrict__ w2,
                                              const unsigned char* __restrict__ w3,
                                              ushort* __restrict__ pred_bf, float* __restrict__ slabel) {
    int b = blockIdx.x * 4 + (threadIdx.x >> 6);
    int lane = threadIdx.x & 63;
    int u = user_seqs[b];
    float hsum = 0.f; int cnt = 0;
    for (int j = 0; j < HIST; ++j) {
        int it = his[b * HIST + j];
        cnt += (it != 0);
        hsum += item_emb[(size_t)it * D + lane];   // item_emb[0] is all-zero (pad)
    }
    int du = deg[u]; if (du < 1) du = 1;
    float su = sqrtf((float)du) * (1.f / 256.f);
    size_t ur = (size_t)u * D + lane;
    float ulat = 0.25f * user_emb[ur] + su * (fp82f(w1[ur]) + fp82f(w2[ur]) + fp82f(w3[ur]));
    float pv = ulat + hsum / (float)cnt;
    pred_bf[(size_t)b * D + lane] = f2bf(pv);
    int lab = next_items[b] - 1;
    int node = N_USERS + lab;
    int di = deg[node]; if (di < 1) di = 1;
    float si = sqrtf((float)di) * (1.f / 256.f);
    size_t nr = (size_t)node * D + lane;
    float ilat = 0.25f * item_emb[(size_t)(lab + 1) * D + lane]
               + si * (fp82f(w1[nr]) + fp82f(w2[nr]) + fp82f(w3[nr]));
    float tv = pv * ilat;
#pragma unroll
    for (int off = 32; off > 0; off >>= 1) tv += __shfl_down(tv, off);
    if (lane == 0) slabel[b] = tv;
}

// ---------------- MFMA scores + max-free sumexp (batch-stationary, frag-tiled items) ----------------
#define MFMA __builtin_amdgcn_mfma_f32_32x32x16_bf16
__global__ __launch_bounds__(256) void k_scores(const ushort* __restrict__ item_bf,
                                                const ushort* __restrict__ pred_bf,
                                                float* __restrict__ sumexp) {
    int t = threadIdx.x, wv = t >> 6, lane = t & 63;
    int l31 = lane & 31;
    int khalf = (lane >> 5) * 8;   // which 8-elem k-half this lane holds

    int brow = blockIdx.y * 128 + wv * 32 + l31;        // this lane's batch column
    const ushort* pb = pred_bf + (size_t)brow * D + khalf;
    short8 b0 = *(const short8*)(pb);
    short8 b1 = *(const short8*)(pb + 16);
    short8 b2 = *(const short8*)(pb + 32);
    short8 b3 = *(const short8*)(pb + 48);

    const ushort* ib = item_bf + (size_t)blockIdx.x * TPS * 2048 + lane * 8;
    float acc = 0.f;

    short8 x0 = *(const short8*)(ib);
    short8 x1 = *(const short8*)(ib + 512);
    short8 x2 = *(const short8*)(ib + 1024);
    short8 x3 = *(const short8*)(ib + 1536);
    short8 x4 = *(const short8*)(ib + 2048);
    short8 x5 = *(const short8*)(ib + 2560);
    short8 x6 = *(const short8*)(ib + 3072);
    short8 x7 = *(const short8*)(ib + 3584);

    for (int tt = 0; tt < TPS; tt += 2) {
        // prefetch next pair (last iteration reads 8KB past this split's tiles —
        // lands in the next split / pred_bf region, valid memory, never used)
        const ushort* in = ib + (size_t)(tt + 2) * 2048;
        short8 y0 = *(const short8*)(in);
        short8 y1 = *(const short8*)(in + 512);
        short8 y2 = *(const short8*)(in + 1024);
        short8 y3 = *(const short8*)(in + 1536);
        short8 y4 = *(const short8*)(in + 2048);
        short8 y5 = *(const short8*)(in + 2560);
        short8 y6 = *(const short8*)(in + 3072);
        short8 y7 = *(const short8*)(in + 3584);
        float16 c0 = {0.f};
        float16 c1 = {0.f};
        c0 = MFMA(x0, b0, c0, 0, 0, 0);
        c1 = MFMA(x4, b0, c1, 0, 0, 0);
        c0 = MFMA(x1, b1, c0, 0, 0, 0);
        c1 = MFMA(x5, b1, c1, 0, 0, 0);
        c0 = MFMA(x2, b2, c0, 0, 0, 0);
        c1 = MFMA(x6, b2, c1, 0, 0, 0);
        c0 = MFMA(x3, b3, c0, 0, 0, 0);
        c1 = MFMA(x7, b3, c1, 0, 0, 0);
        float s0 = 0.f, s1 = 0.f, s2 = 0.f, s3 = 0.f;
#pragma unroll
        for (int r = 0; r < 16; r += 4) {
            s0 += exp2fast(c0[r]);
            s1 += exp2fast(c0[r + 1]);
            s2 += exp2fast(c0[r + 2]);
            s3 += exp2fast(c0[r + 3]);
        }
#pragma unroll
        for (int r = 0; r < 16; r += 4) {
            s0 += exp2fast(c1[r]);
            s1 += exp2fast(c1[r + 1]);
            s2 += exp2fast(c1[r + 2]);
            s3 += exp2fast(c1[r + 3]);
        }
        acc += (s0 + s1) + (s2 + s3);
        x0 = y0; x1 = y1; x2 = y2; x3 = y3;
        x4 = y4; x5 = y5; x6 = y6; x7 = y7;
    }
    // lane L and L+32 hold the two item-row halves of the same batch col
    acc += __shfl_down(acc, 32);
    if (lane < 32) unsafeAtomicAdd(&sumexp[brow], acc);
}

// ---------------- final loss reduce ----------------
__global__ __launch_bounds__(256) void k_loss(const float* __restrict__ sumexp, const float* __restrict__ slabel,
                                              float* __restrict__ out) {
    __shared__ float ws[4];
    int t = threadIdx.x;
    float v = 0.f;
    for (int i = t; i < BATCH; i += 256)
        v += __logf(sumexp[i] - 96.0f) - slabel[i];   // -96: padded items contribute exp2(0)=1 each
#pragma unroll
    for (int off = 32; off > 0; off >>= 1) v += __shfl_down(v, off);
    if ((t & 63) == 0) ws[t >> 6] = v;
    __syncthreads();
    if (t == 0) out[0] = (ws[0] + ws[1] + ws[2] + ws[3]) * (1.f / (float)BATCH);
}

extern "C" void kernel_launch(void* const* d_in, const int* in_sizes, int n_in,
                              void* d_out, int out_size, void* d_ws, size_t ws_size,
                              hipStream_t stream) {
    const int*   user_seqs = (const int*)d_in[0];
    const int*   his       = (const int*)d_in[1];
    const int*   next_itm  = (const int*)d_in[2];
    const int*   adj_row   = (const int*)d_in[3];
    const int*   adj_col   = (const int*)d_in[4];
    const float* user_emb  = (const float*)d_in[6];
    const float* item_emb  = (const float*)d_in[7];
    float* out = (float*)d_out;
    int nedges = in_sizes[3];   // 12,800,000

    // Workspace layout (~183 MB). gcursor padded to 512 ints so every downstream
    // buffer stays 256B-aligned.
    unsigned char* w0 = (unsigned char*)d_ws;              // 12.8 MB each
    unsigned char* w1 = w0 + (size_t)N_NODES * D;
    unsigned char* w2 = w1 + (size_t)N_NODES * D;
    unsigned char* w3 = w2 + (size_t)N_NODES * D;
    float*  slabel = (float*)(w3 + (size_t)N_NODES * D);   // 2,048
    float*  sumexp = slabel + BATCH;                       // 2,048   (zeroed)
    int*    gcursor= (int*)(sumexp + BATCH);               // 512 (zeroed; 196 used)
    int*    rowptr = gcursor + 512;                        // 200,000
    int*    deg    = rowptr + N_NODES;                     // 200,000
    int*    staged = deg + N_NODES;                        // 196*73728 ints (57.8 MB)
    int*    ecols  = staged + (size_t)N_BUCKETS_RAW * BCAP; // 196*73728 ints (57.8 MB)
    ushort* item_bf = (ushort*)(ecols + (size_t)N_BUCKETS_RAW * BCAP);  // 100096*64 ushort, 256B-aligned
    ushort* pred_bf = item_bf + (size_t)N_ITEMS_PAD * D;   // 131072 ushort

    // zero sumexp + gcursor in one shot (contiguous)
    hipError_t _e = hipMemsetAsync(sumexp, 0, (size_t)(BATCH + 512) * sizeof(int), stream);
    (void)_e;

    int nchunks = (nedges + CHUNK - 1) / CHUNK;
    k_binA<<<nchunks, 256, 0, stream>>>(adj_row, adj_col, gcursor, staged, nedges);
    k_binB<<<N_BUCKETS_RAW, 1024, 0, stream>>>(gcursor, staged, ecols, rowptr, deg,
                                               user_emb, item_emb, w0);

    k_prop<<<N_NODES / 32, 256, 0, stream>>>(rowptr, deg, ecols, w0, w1);
    k_prop<<<N_NODES / 32, 256, 0, stream>>>(rowptr, deg, ecols, w1, w2);
    k_prop<<<N_NODES / 32, 256, 0, stream>>>(rowptr, deg, ecols, w2, w3);

    k_conv_items<<<(N_ITEMS_PAD * (D / 4) + 255) / 256, 256, 0, stream>>>(item_emb, deg, w1, w2, w3, item_bf);
    k_pred<<<BATCH / 4, 256, 0, stream>>>(user_seqs, his, next_itm, user_emb, item_emb, deg,
                                          w1, w2, w3, pred_bf, slabel);

    dim3 gs(ISPLITS, BATCH / 128);
    k_scores<<<gs, 256, 0, stream>>>(item_bf, pred_bf, sumexp);

    k_loss<<<1, 256, 0, stream>>>(sumexp, slabel, out);
}